// Round 4
// baseline (253.226 us; speedup 1.0000x reference)
//
#include <hip/hip_runtime.h>
#include <stdint.h>

// QuantizedLinear: out = x @ dequant(q,s)^T + bias
#define M_DIM 2048
#define K_DIM 4096
#define N_DIM 11008
#define KB2   (K_DIM / 2)
#define NGRP  (K_DIM / 128)

// main GEMM tile: 128x256, BK=32, 256 threads (4 waves, 2Mx2N, wave tile 64x128)
#define TBM 128
#define TBN 256
#define TBK 32
#define NT  (K_DIM / TBK)     // 128 K-steps
#define BUF_U 12288           // ushorts per LDS buffer: A 128x32 (4096) + B 256x32 (8192) = 24KB
                              // 3 buffers = 72KB -> 2 blocks/CU

// fallback tile
#define BM 128
#define BN 128
#define BK 64

typedef __attribute__((ext_vector_type(8))) short bf16x8;
typedef __attribute__((ext_vector_type(4))) float f32x4;

__device__ __forceinline__ unsigned short f2bf(float f) {
  union { float f; unsigned u; } v; v.f = f;
  return (unsigned short)((v.u + 0x7FFFu + ((v.u >> 16) & 1u)) >> 16);
}

__device__ __forceinline__ void gload_lds16(const void* g, void* l) {
  __builtin_amdgcn_global_load_lds(
      (__attribute__((address_space(1))) void*)(g),
      (__attribute__((address_space(3))) void*)(l), 16, 0, 0);
}

// ---------------- prepass: x f32 -> bf16 ----------------
__global__ void convert_x_kernel(const float* __restrict__ x,
                                 unsigned short* __restrict__ xb) {
  const size_t total = (size_t)M_DIM * K_DIM / 8;
  for (size_t u = (size_t)blockIdx.x * blockDim.x + threadIdx.x; u < total;
       u += (size_t)gridDim.x * blockDim.x) {
    const float4* src = (const float4*)(x + u * 8);
    float4 f0 = src[0];
    float4 f1 = src[1];
    union { unsigned short h[8]; int4 v; } o;
    o.h[0] = f2bf(f0.x); o.h[1] = f2bf(f0.y); o.h[2] = f2bf(f0.z); o.h[3] = f2bf(f0.w);
    o.h[4] = f2bf(f1.x); o.h[5] = f2bf(f1.y); o.h[6] = f2bf(f1.z); o.h[7] = f2bf(f1.w);
    *(int4*)(xb + u * 8) = o.v;
  }
}

// ---------------- prepass: packed int4 -> bf16 W [N, K] ----------------
__global__ void dequant_w_kernel(const int* __restrict__ q,
                                 const float* __restrict__ s,
                                 unsigned short* __restrict__ W) {
  const size_t total = (size_t)N_DIM * KB2 / 4;
  for (size_t u = (size_t)blockIdx.x * blockDim.x + threadIdx.x; u < total;
       u += (size_t)gridDim.x * blockDim.x) {
    size_t qi = u * 4;
    unsigned o = (unsigned)(qi >> 11);
    unsigned c = (unsigned)(qi & 2047);
    float sc = s[o * NGRP + (c >> 6)];
    int4 qv = *(const int4*)(q + qi);
    union { unsigned short h[8]; int4 v; } w;
    int b;
    b = qv.x; w.h[0] = f2bf((float)((b & 15) - 8) * sc); w.h[1] = f2bf((float)(((b >> 4) & 15) - 8) * sc);
    b = qv.y; w.h[2] = f2bf((float)((b & 15) - 8) * sc); w.h[3] = f2bf((float)(((b >> 4) & 15) - 8) * sc);
    b = qv.z; w.h[4] = f2bf((float)((b & 15) - 8) * sc); w.h[5] = f2bf((float)(((b >> 4) & 15) - 8) * sc);
    b = qv.w; w.h[6] = f2bf((float)((b & 15) - 8) * sc); w.h[7] = f2bf((float)(((b >> 4) & 15) - 8) * sc);
    *(int4*)(W + qi * 2) = w.v;
  }
}

// ---------------- main GEMM: C = A[M,K] * B[N,K]^T + bias ----------------
// 128x256 tile, BK=32, 4 waves (2M x 2N), per-wave 64x128 = acc[4][8].
// 72KB LDS (3 x 24KB) -> 2 independent blocks/CU: each SIMD holds 2 waves
// from DIFFERENT blocks, so barrier/vmcnt stalls of one block overlap the
// other block's MFMA cluster (no instruction pinning needed).
// 3-buffer pipeline, distance-2 prefetch, counted vmcnt(6) (6 loads/tile).
// Swizzle (row stride 64B, 4 x 16B slots): write global-k offset
// (slot ^ (row&3))*8, read k-offset (lq ^ (row&3))*8 -> 2-way = free.
__global__ __launch_bounds__(256, 2) void gemm_pipe_kernel(
    const unsigned short* __restrict__ A, const unsigned short* __restrict__ B,
    const float* __restrict__ bias, float* __restrict__ C) {
  __shared__ unsigned short lds[3 * BUF_U];  // 72 KB

  const int tid = threadIdx.x;
  const int w = tid >> 6, lane = tid & 63;

  // T1: XCD-chunked bijective swizzle (688 = 8 * 86); m cycles fast within an
  // XCD so the 2MB B-panel stays L2-resident across 16 consecutive blocks.
  const int hw = blockIdx.x;
  const int wg = (hw & 7) * 86 + (hw >> 3);
  const int m0 = (wg % 16) * TBM;
  const int n0 = (wg / 16) * TBN;

  // staging: 6 issues/tile (A:2, B:4), each issue = 256 threads x 16B = 64 rows.
  // thread row-within-issue = tid>>2, slot = tid&3; inverse swizzle on global k.
  const int srow = tid >> 2;
  const int kx = (((tid & 3) ^ ((tid >> 2) & 3)) << 3);
  const unsigned short* Ag = A + (size_t)(m0 + srow) * K_DIM + kx;
  const unsigned short* Bg = B + (size_t)(n0 + srow) * K_DIM + kx;
  const int wBase = w * 512;  // wave-uniform LDS staging base offset (ushorts)

#define STAGE(bufo, t2) {                                                      \
    const unsigned short* a_ = Ag + (size_t)(t2) * TBK;                        \
    const unsigned short* b_ = Bg + (size_t)(t2) * TBK;                        \
    gload_lds16(a_,                        lds + (bufo) + wBase);              \
    gload_lds16(a_ + (size_t)64 * K_DIM,   lds + (bufo) + wBase + 2048);       \
    gload_lds16(b_,                        lds + (bufo) + wBase + 4096);       \
    gload_lds16(b_ + (size_t)64 * K_DIM,   lds + (bufo) + wBase + 6144);       \
    gload_lds16(b_ + (size_t)128 * K_DIM,  lds + (bufo) + wBase + 8192);       \
    gload_lds16(b_ + (size_t)192 * K_DIM,  lds + (bufo) + wBase + 10240);      \
  }

  // ds_read addressing (swizzled): addr = row*32 + ((lq)^(row&3))*8
  const int lane16 = lane & 15, lq = lane >> 4, rx3 = lane16 & 3;
  const int wm = (w >> 1) * 64, wn = (w & 1) * 128;
  const int kOfs = (lq ^ rx3) << 3;
  int aRow[4], bRow[8];
#pragma unroll
  for (int i = 0; i < 4; ++i) aRow[i] = (wm + i * 16 + lane16) * 32 + kOfs;
#pragma unroll
  for (int j = 0; j < 8; ++j) bRow[j] = 4096 + (wn + j * 16 + lane16) * 32 + kOfs;

  f32x4 acc[4][8] = {};

  // prologue: stage tiles 0,1 (12 loads); wait for tile 0's 6
  STAGE(0, 0);
  STAGE(BUF_U, 1);
  asm volatile("s_waitcnt vmcnt(6)" ::: "memory");
  __builtin_amdgcn_s_barrier();

  int cur = 0, stg = 2 * BUF_U;
  for (int t = 0; t < NT; ++t) {
    if (t + 2 < NT) STAGE(stg, t + 2);

    const unsigned short* Lb = lds + cur;
    bf16x8 av[4], bv[8];
#pragma unroll
    for (int i = 0; i < 4; ++i) av[i] = *(const bf16x8*)&Lb[aRow[i]];
#pragma unroll
    for (int j = 0; j < 8; ++j) bv[j] = *(const bf16x8*)&Lb[bRow[j]];

    __builtin_amdgcn_s_setprio(1);
#pragma unroll
    for (int i = 0; i < 4; ++i)
#pragma unroll
      for (int j = 0; j < 8; ++j)
        acc[i][j] = __builtin_amdgcn_mfma_f32_16x16x32_bf16(av[i], bv[j], acc[i][j], 0, 0, 0);
    __builtin_amdgcn_s_setprio(0);

    if (t == NT - 1) break;
    if (t == NT - 2) {
      asm volatile("s_waitcnt vmcnt(0)" ::: "memory");  // final tile must land
    } else {
      asm volatile("s_waitcnt vmcnt(6)" ::: "memory");  // keep tile t+2 in flight
    }
    __builtin_amdgcn_s_barrier();
    cur = (cur == 2 * BUF_U) ? 0 : cur + BUF_U;
    stg = (stg == 2 * BUF_U) ? 0 : stg + BUF_U;
  }
#undef STAGE

  // epilogue: D mapping col=lane&15, row=(lane>>4)*4+r
  const int row0 = m0 + wm + (lane >> 4) * 4;
  const int col0 = n0 + wn + lane16;
#pragma unroll
  for (int j = 0; j < 8; ++j) {
    float bvs = bias[col0 + j * 16];
#pragma unroll
    for (int i = 0; i < 4; ++i) {
#pragma unroll
      for (int r = 0; r < 4; ++r) {
        C[(size_t)(row0 + i * 16 + r) * N_DIM + (col0 + j * 16)] = acc[i][j][r] + bvs;
      }
    }
  }
}

// ---------------- fallback: fused dequant GEMM (no workspace needed) ----------------
__global__ __launch_bounds__(256, 2) void gemm_fused_kernel(
    const float* __restrict__ x, const int* __restrict__ q,
    const float* __restrict__ s, const float* __restrict__ bias,
    float* __restrict__ C) {
  __shared__ unsigned short As[BM * BK];
  __shared__ unsigned short Bs[BN * BK];

  const int tid = threadIdx.x;
  const int wave = tid >> 6, lane = tid & 63;
  const int m0 = blockIdx.y * BM, n0 = blockIdx.x * BN;
  const int wm = (wave >> 1) * 64, wn = (wave & 1) * 64;

  f32x4 acc[4][4] = {};

  const int r2 = tid >> 1;
  const int kh = (tid & 1) * 32;
  const float* xg = x + (size_t)(m0 + r2) * K_DIM + kh;
  const int* qg = q + (size_t)(n0 + r2) * KB2 + (tid & 1) * 16;
  const float* sg = s + (size_t)(n0 + r2) * NGRP;
  unsigned short* Asp = &As[r2 * BK + kh];
  unsigned short* Bsp = &Bs[r2 * BK + kh];

  const int lane16 = lane & 15;
  const int kq = (lane >> 4) * 8;

  for (int t = 0; t < K_DIM / BK; ++t) {
    union { unsigned short h[8]; bf16x8 v; } oA[4], oB[4];
#pragma unroll
    for (int j = 0; j < 4; ++j) {
      float4 f0 = *(const float4*)(xg + t * BK + j * 8);
      float4 f1 = *(const float4*)(xg + t * BK + j * 8 + 4);
      oA[j].h[0] = f2bf(f0.x); oA[j].h[1] = f2bf(f0.y); oA[j].h[2] = f2bf(f0.z); oA[j].h[3] = f2bf(f0.w);
      oA[j].h[4] = f2bf(f1.x); oA[j].h[5] = f2bf(f1.y); oA[j].h[6] = f2bf(f1.z); oA[j].h[7] = f2bf(f1.w);
    }
    float sc = sg[t >> 1];
#pragma unroll
    for (int j = 0; j < 4; ++j) {
      int4 qv = *(const int4*)(qg + t * 32 + j * 4);
      int b;
      b = qv.x; oB[j].h[0] = f2bf((float)((b & 15) - 8) * sc); oB[j].h[1] = f2bf((float)(((b >> 4) & 15) - 8) * sc);
      b = qv.y; oB[j].h[2] = f2bf((float)((b & 15) - 8) * sc); oB[j].h[3] = f2bf((float)(((b >> 4) & 15) - 8) * sc);
      b = qv.z; oB[j].h[4] = f2bf((float)((b & 15) - 8) * sc); oB[j].h[5] = f2bf((float)(((b >> 4) & 15) - 8) * sc);
      b = qv.w; oB[j].h[6] = f2bf((float)((b & 15) - 8) * sc); oB[j].h[7] = f2bf((float)(((b >> 4) & 15) - 8) * sc);
    }
    __syncthreads();
#pragma unroll
    for (int j = 0; j < 4; ++j) {
      *(bf16x8*)(Asp + j * 8) = oA[j].v;
      *(bf16x8*)(Bsp + j * 8) = oB[j].v;
    }
    __syncthreads();
#pragma unroll
    for (int kk = 0; kk < 2; ++kk) {
      const int ko = kk * 32 + kq;
      bf16x8 av[4], bv[4];
#pragma unroll
      for (int i = 0; i < 4; ++i)
        av[i] = *(const bf16x8*)&As[(wm + i * 16 + lane16) * BK + ko];
#pragma unroll
      for (int i = 0; i < 4; ++i)
        bv[i] = *(const bf16x8*)&Bs[(wn + i * 16 + lane16) * BK + ko];
#pragma unroll
      for (int i = 0; i < 4; ++i)
#pragma unroll
        for (int j = 0; j < 4; ++j)
          acc[i][j] = __builtin_amdgcn_mfma_f32_16x16x32_bf16(av[i], bv[j], acc[i][j], 0, 0, 0);
    }
  }

  const int col0 = n0 + wn + lane16;
  const int row0 = m0 + wm + (lane >> 4) * 4;
#pragma unroll
  for (int j = 0; j < 4; ++j) {
    float bvs = bias[col0 + j * 16];
#pragma unroll
    for (int i = 0; i < 4; ++i) {
#pragma unroll
      for (int r = 0; r < 4; ++r) {
        C[(size_t)(row0 + i * 16 + r) * N_DIM + (col0 + j * 16)] = acc[i][j][r] + bvs;
      }
    }
  }
}

extern "C" void kernel_launch(void* const* d_in, const int* in_sizes, int n_in,
                              void* d_out, int out_size, void* d_ws, size_t ws_size,
                              hipStream_t stream) {
  const float* x = (const float*)d_in[0];
  const int* q = (const int*)d_in[1];
  const float* s = (const float*)d_in[2];
  const float* b = (const float*)d_in[3];
  float* out = (float*)d_out;

  const size_t wb_elems = (size_t)N_DIM * K_DIM;
  const size_t ab_elems = (size_t)M_DIM * K_DIM;
  const size_t need = (wb_elems + ab_elems) * sizeof(unsigned short);

  if (ws_size >= need) {
    unsigned short* Wb = (unsigned short*)d_ws;
    unsigned short* Ab = Wb + wb_elems;
    convert_x_kernel<<<dim3(2048), dim3(256), 0, stream>>>(x, Ab);
    dequant_w_kernel<<<dim3(4096), dim3(256), 0, stream>>>(q, s, Wb);
    gemm_pipe_kernel<<<dim3((N_DIM / TBN) * (M_DIM / TBM)), dim3(256), 0, stream>>>(Ab, Wb, b, out);
  } else {
    gemm_fused_kernel<<<dim3(N_DIM / BN, M_DIM / BM), dim3(256), 0, stream>>>(x, q, s, b, out);
  }
}

// Round 5
// 245.717 us; speedup vs baseline: 1.0306x; 1.0306x over previous
//
#include <hip/hip_runtime.h>
#include <stdint.h>

// QuantizedLinear: out = x @ dequant(q,s)^T + bias
#define M_DIM 2048
#define K_DIM 4096
#define N_DIM 11008
#define KB2   (K_DIM / 2)
#define NGRP  (K_DIM / 128)

// main GEMM tile: 128x256, BK=32, 256 threads (4 waves, 2Mx2N, wave tile 64x128)
#define TBM 128
#define TBN 256
#define TBK 32
#define NT  (K_DIM / TBK)     // 128 K-steps
#define BUF_U 12288           // ushorts per LDS buffer: A 128x32 (4096) + B 256x32 (8192) = 24KB
                              // 3 buffers = 72KB -> 2 blocks/CU

// fallback tile
#define BM 128
#define BN 128
#define BK 64

typedef __attribute__((ext_vector_type(8))) short bf16x8;
typedef __attribute__((ext_vector_type(4))) float f32x4;

__device__ __forceinline__ unsigned short f2bf(float f) {
  union { float f; unsigned u; } v; v.f = f;
  return (unsigned short)((v.u + 0x7FFFu + ((v.u >> 16) & 1u)) >> 16);
}

__device__ __forceinline__ void gload_lds16(const void* g, void* l) {
  __builtin_amdgcn_global_load_lds(
      (__attribute__((address_space(1))) void*)(g),
      (__attribute__((address_space(3))) void*)(l), 16, 0, 0);
}

// ---------------- prepass: x f32 -> bf16 ----------------
__global__ void convert_x_kernel(const float* __restrict__ x,
                                 unsigned short* __restrict__ xb) {
  const size_t total = (size_t)M_DIM * K_DIM / 8;
  for (size_t u = (size_t)blockIdx.x * blockDim.x + threadIdx.x; u < total;
       u += (size_t)gridDim.x * blockDim.x) {
    const float4* src = (const float4*)(x + u * 8);
    float4 f0 = src[0];
    float4 f1 = src[1];
    union { unsigned short h[8]; int4 v; } o;
    o.h[0] = f2bf(f0.x); o.h[1] = f2bf(f0.y); o.h[2] = f2bf(f0.z); o.h[3] = f2bf(f0.w);
    o.h[4] = f2bf(f1.x); o.h[5] = f2bf(f1.y); o.h[6] = f2bf(f1.z); o.h[7] = f2bf(f1.w);
    *(int4*)(xb + u * 8) = o.v;
  }
}

// ---------------- prepass: packed int4 -> bf16 W [N, K] ----------------
__global__ void dequant_w_kernel(const int* __restrict__ q,
                                 const float* __restrict__ s,
                                 unsigned short* __restrict__ W) {
  const size_t total = (size_t)N_DIM * KB2 / 4;
  for (size_t u = (size_t)blockIdx.x * blockDim.x + threadIdx.x; u < total;
       u += (size_t)gridDim.x * blockDim.x) {
    size_t qi = u * 4;
    unsigned o = (unsigned)(qi >> 11);
    unsigned c = (unsigned)(qi & 2047);
    float sc = s[o * NGRP + (c >> 6)];
    int4 qv = *(const int4*)(q + qi);
    union { unsigned short h[8]; int4 v; } w;
    int b;
    b = qv.x; w.h[0] = f2bf((float)((b & 15) - 8) * sc); w.h[1] = f2bf((float)(((b >> 4) & 15) - 8) * sc);
    b = qv.y; w.h[2] = f2bf((float)((b & 15) - 8) * sc); w.h[3] = f2bf((float)(((b >> 4) & 15) - 8) * sc);
    b = qv.z; w.h[4] = f2bf((float)((b & 15) - 8) * sc); w.h[5] = f2bf((float)(((b >> 4) & 15) - 8) * sc);
    b = qv.w; w.h[6] = f2bf((float)((b & 15) - 8) * sc); w.h[7] = f2bf((float)(((b >> 4) & 15) - 8) * sc);
    *(int4*)(W + qi * 2) = w.v;
  }
}

// ---------------- main GEMM: C = A[M,K] * B[N,K]^T + bias ----------------
// 128x256 tile, BK=32, 4 waves (2M x 2N), per-wave 64x128 = acc[4][8].
// 72KB LDS (3 x 24KB) -> 2 independent blocks/CU.
// 3-buffer pipeline, distance-2 prefetch, counted vmcnt(6) (6 loads/tile).
// Swizzle for 64B row stride (bank base = (row%2)*16 + slot*4):
//   XOR the 16B slot with f(row) = (row>>1)&3  -> every 4-bank span gets
//   exactly 8 lanes over the 8 service cycles of a wave b128 = conflict-free.
// Both-sides (rule 21): linear gload_lds dest + inverse-swizzled global k
// (slot ^ (srow>>1)&3) + swizzled ds_read (lq ^ (row>>1)&3).
__global__ __launch_bounds__(256, 2) void gemm_pipe_kernel(
    const unsigned short* __restrict__ A, const unsigned short* __restrict__ B,
    const float* __restrict__ bias, float* __restrict__ C) {
  __shared__ unsigned short lds[3 * BUF_U];  // 72 KB

  const int tid = threadIdx.x;
  const int w = tid >> 6, lane = tid & 63;

  // T1: XCD-chunked bijective swizzle (688 = 8 * 86); m cycles fast within an
  // XCD so the 2MB B-panel stays L2-resident across 16 consecutive blocks.
  const int hw = blockIdx.x;
  const int wg = (hw & 7) * 86 + (hw >> 3);
  const int m0 = (wg % 16) * TBM;
  const int n0 = (wg / 16) * TBN;

  // staging: 6 issues/tile (A:2, B:4), each issue = 256 threads x 16B = 64 rows.
  // thread row-within-issue = tid>>2, slot = tid&3.
  // Inverse swizzle on global k: slot s of row r holds k-chunk s ^ ((r>>1)&3).
  const int srow = tid >> 2;
  const int kx = (((tid & 3) ^ ((tid >> 3) & 3)) << 3);
  const unsigned short* Ag = A + (size_t)(m0 + srow) * K_DIM + kx;
  const unsigned short* Bg = B + (size_t)(n0 + srow) * K_DIM + kx;
  const int wBase = w * 512;  // wave-uniform LDS staging base offset (ushorts)

#define STAGE(bufo, t2) {                                                      \
    const unsigned short* a_ = Ag + (size_t)(t2) * TBK;                        \
    const unsigned short* b_ = Bg + (size_t)(t2) * TBK;                        \
    gload_lds16(a_,                        lds + (bufo) + wBase);              \
    gload_lds16(a_ + (size_t)64 * K_DIM,   lds + (bufo) + wBase + 2048);       \
    gload_lds16(b_,                        lds + (bufo) + wBase + 4096);       \
    gload_lds16(b_ + (size_t)64 * K_DIM,   lds + (bufo) + wBase + 6144);       \
    gload_lds16(b_ + (size_t)128 * K_DIM,  lds + (bufo) + wBase + 8192);       \
    gload_lds16(b_ + (size_t)192 * K_DIM,  lds + (bufo) + wBase + 10240);      \
  }

  // ds_read addressing (swizzled): addr = row*32 + (lq ^ ((row>>1)&3))*8.
  // wm and i*16 are multiples of 16, so (row>>1)&3 = (lane16>>1)&3 for all
  // fragments -> one kOfs per lane.
  const int lane16 = lane & 15, lq = lane >> 4;
  const int wm = (w >> 1) * 64, wn = (w & 1) * 128;
  const int kOfs = (lq ^ ((lane16 >> 1) & 3)) << 3;
  int aRow[4], bRow[8];
#pragma unroll
  for (int i = 0; i < 4; ++i) aRow[i] = (wm + i * 16 + lane16) * 32 + kOfs;
#pragma unroll
  for (int j = 0; j < 8; ++j) bRow[j] = 4096 + (wn + j * 16 + lane16) * 32 + kOfs;

  f32x4 acc[4][8] = {};

  // prologue: stage tiles 0,1 (12 loads); wait for tile 0's 6
  STAGE(0, 0);
  STAGE(BUF_U, 1);
  asm volatile("s_waitcnt vmcnt(6)" ::: "memory");
  __builtin_amdgcn_s_barrier();

  int cur = 0, stg = 2 * BUF_U;
  for (int t = 0; t < NT; ++t) {
    if (t + 2 < NT) STAGE(stg, t + 2);

    const unsigned short* Lb = lds + cur;
    bf16x8 av[4], bv[8];
#pragma unroll
    for (int i = 0; i < 4; ++i) av[i] = *(const bf16x8*)&Lb[aRow[i]];
#pragma unroll
    for (int j = 0; j < 8; ++j) bv[j] = *(const bf16x8*)&Lb[bRow[j]];

    __builtin_amdgcn_s_setprio(1);
#pragma unroll
    for (int i = 0; i < 4; ++i)
#pragma unroll
      for (int j = 0; j < 8; ++j)
        acc[i][j] = __builtin_amdgcn_mfma_f32_16x16x32_bf16(av[i], bv[j], acc[i][j], 0, 0, 0);
    __builtin_amdgcn_s_setprio(0);

    if (t == NT - 1) break;
    if (t == NT - 2) {
      asm volatile("s_waitcnt vmcnt(0)" ::: "memory");  // final tile must land
    } else {
      asm volatile("s_waitcnt vmcnt(6)" ::: "memory");  // keep tile t+2 in flight
    }
    __builtin_amdgcn_s_barrier();
    cur = (cur == 2 * BUF_U) ? 0 : cur + BUF_U;
    stg = (stg == 2 * BUF_U) ? 0 : stg + BUF_U;
  }
#undef STAGE

  // epilogue: D mapping col=lane&15, row=(lane>>4)*4+r
  const int row0 = m0 + wm + (lane >> 4) * 4;
  const int col0 = n0 + wn + lane16;
#pragma unroll
  for (int j = 0; j < 8; ++j) {
    float bvs = bias[col0 + j * 16];
#pragma unroll
    for (int i = 0; i < 4; ++i) {
#pragma unroll
      for (int r = 0; r < 4; ++r) {
        C[(size_t)(row0 + i * 16 + r) * N_DIM + (col0 + j * 16)] = acc[i][j][r] + bvs;
      }
    }
  }
}

// ---------------- fallback: fused dequant GEMM (no workspace needed) ----------------
__global__ __launch_bounds__(256, 2) void gemm_fused_kernel(
    const float* __restrict__ x, const int* __restrict__ q,
    const float* __restrict__ s, const float* __restrict__ bias,
    float* __restrict__ C) {
  __shared__ unsigned short As[BM * BK];
  __shared__ unsigned short Bs[BN * BK];

  const int tid = threadIdx.x;
  const int wave = tid >> 6, lane = tid & 63;
  const int m0 = blockIdx.y * BM, n0 = blockIdx.x * BN;
  const int wm = (wave >> 1) * 64, wn = (wave & 1) * 64;

  f32x4 acc[4][4] = {};

  const int r2 = tid >> 1;
  const int kh = (tid & 1) * 32;
  const float* xg = x + (size_t)(m0 + r2) * K_DIM + kh;
  const int* qg = q + (size_t)(n0 + r2) * KB2 + (tid & 1) * 16;
  const float* sg = s + (size_t)(n0 + r2) * NGRP;
  unsigned short* Asp = &As[r2 * BK + kh];
  unsigned short* Bsp = &Bs[r2 * BK + kh];

  const int lane16 = lane & 15;
  const int kq = (lane >> 4) * 8;

  for (int t = 0; t < K_DIM / BK; ++t) {
    union { unsigned short h[8]; bf16x8 v; } oA[4], oB[4];
#pragma unroll
    for (int j = 0; j < 4; ++j) {
      float4 f0 = *(const float4*)(xg + t * BK + j * 8);
      float4 f1 = *(const float4*)(xg + t * BK + j * 8 + 4);
      oA[j].h[0] = f2bf(f0.x); oA[j].h[1] = f2bf(f0.y); oA[j].h[2] = f2bf(f0.z); oA[j].h[3] = f2bf(f0.w);
      oA[j].h[4] = f2bf(f1.x); oA[j].h[5] = f2bf(f1.y); oA[j].h[6] = f2bf(f1.z); oA[j].h[7] = f2bf(f1.w);
    }
    float sc = sg[t >> 1];
#pragma unroll
    for (int j = 0; j < 4; ++j) {
      int4 qv = *(const int4*)(qg + t * 32 + j * 4);
      int b;
      b = qv.x; oB[j].h[0] = f2bf((float)((b & 15) - 8) * sc); oB[j].h[1] = f2bf((float)(((b >> 4) & 15) - 8) * sc);
      b = qv.y; oB[j].h[2] = f2bf((float)((b & 15) - 8) * sc); oB[j].h[3] = f2bf((float)(((b >> 4) & 15) - 8) * sc);
      b = qv.z; oB[j].h[4] = f2bf((float)((b & 15) - 8) * sc); oB[j].h[5] = f2bf((float)(((b >> 4) & 15) - 8) * sc);
      b = qv.w; oB[j].h[6] = f2bf((float)((b & 15) - 8) * sc); oB[j].h[7] = f2bf((float)(((b >> 4) & 15) - 8) * sc);
    }
    __syncthreads();
#pragma unroll
    for (int j = 0; j < 4; ++j) {
      *(bf16x8*)(Asp + j * 8) = oA[j].v;
      *(bf16x8*)(Bsp + j * 8) = oB[j].v;
    }
    __syncthreads();
#pragma unroll
    for (int kk = 0; kk < 2; ++kk) {
      const int ko = kk * 32 + kq;
      bf16x8 av[4], bv[4];
#pragma unroll
      for (int i = 0; i < 4; ++i)
        av[i] = *(const bf16x8*)&As[(wm + i * 16 + lane16) * BK + ko];
#pragma unroll
      for (int i = 0; i < 4; ++i)
        bv[i] = *(const bf16x8*)&Bs[(wn + i * 16 + lane16) * BK + ko];
#pragma unroll
      for (int i = 0; i < 4; ++i)
#pragma unroll
        for (int j = 0; j < 4; ++j)
          acc[i][j] = __builtin_amdgcn_mfma_f32_16x16x32_bf16(av[i], bv[j], acc[i][j], 0, 0, 0);
    }
  }

  const int col0 = n0 + wn + lane16;
  const int row0 = m0 + wm + (lane >> 4) * 4;
#pragma unroll
  for (int j = 0; j < 4; ++j) {
    float bvs = bias[col0 + j * 16];
#pragma unroll
    for (int i = 0; i < 4; ++i) {
#pragma unroll
      for (int r = 0; r < 4; ++r) {
        C[(size_t)(row0 + i * 16 + r) * N_DIM + (col0 + j * 16)] = acc[i][j][r] + bvs;
      }
    }
  }
}

extern "C" void kernel_launch(void* const* d_in, const int* in_sizes, int n_in,
                              void* d_out, int out_size, void* d_ws, size_t ws_size,
                              hipStream_t stream) {
  const float* x = (const float*)d_in[0];
  const int* q = (const int*)d_in[1];
  const float* s = (const float*)d_in[2];
  const float* b = (const float*)d_in[3];
  float* out = (float*)d_out;

  const size_t wb_elems = (size_t)N_DIM * K_DIM;
  const size_t ab_elems = (size_t)M_DIM * K_DIM;
  const size_t need = (wb_elems + ab_elems) * sizeof(unsigned short);

  if (ws_size >= need) {
    unsigned short* Wb = (unsigned short*)d_ws;
    unsigned short* Ab = Wb + wb_elems;
    convert_x_kernel<<<dim3(2048), dim3(256), 0, stream>>>(x, Ab);
    dequant_w_kernel<<<dim3(4096), dim3(256), 0, stream>>>(q, s, Wb);
    gemm_pipe_kernel<<<dim3((N_DIM / TBN) * (M_DIM / TBM)), dim3(256), 0, stream>>>(Ab, Wb, b, out);
  } else {
    gemm_fused_kernel<<<dim3(N_DIM / BN, M_DIM / BM), dim3(256), 0, stream>>>(x, q, s, b, out);
  }
}

// Round 6
// 195.703 us; speedup vs baseline: 1.2939x; 1.2556x over previous
//
#include <hip/hip_runtime.h>
#include <stdint.h>

// QuantizedLinear: out = x @ dequant(q,s)^T + bias
// i8-MFMA path: weights (nib-8) exact in i8; x quantized at fixed scale;
// group scales applied exactly via per-128K i32->f32 fixup.
#define M_DIM 2048
#define K_DIM 4096
#define N_DIM 11008
#define KB2   (K_DIM / 2)
#define NGRP  32

// main GEMM tile: 128x256, BK=64 (i8), 512 threads (8 waves, 2Mx4N, wave 64x64)
#define TBM 128
#define TBN 256
#define TBK 64
#define NT  (K_DIM / TBK)     // 64 K-steps
#define BUF_B 24576           // bytes per LDS buffer: A 128x64 + B 256x64 (i8)
#define SLDS_OFF (3 * BUF_B)  // scale tile at 73728 (8192 floats = 32KB); total 104KB

#define XRANGE 5.0f
#define XSCALE (127.0f / XRANGE)
#define XINV   (XRANGE / 127.0f)

// fallback tile (bf16 fused path, no workspace)
#define BM 128
#define BN 128
#define BK 64

typedef __attribute__((ext_vector_type(4))) int   i32x4;
typedef __attribute__((ext_vector_type(4))) float f32x4;
typedef __attribute__((ext_vector_type(8))) short bf16x8;

__device__ __forceinline__ unsigned short f2bf(float f) {
  union { float f; unsigned u; } v; v.f = f;
  return (unsigned short)((v.u + 0x7FFFu + ((v.u >> 16) & 1u)) >> 16);
}

__device__ __forceinline__ void gload_lds16(const void* g, void* l) {
  __builtin_amdgcn_global_load_lds(
      (__attribute__((address_space(1))) void*)(g),
      (__attribute__((address_space(3))) void*)(l), 16, 0, 0);
}

__device__ __forceinline__ int q127(float v) {
  float qf = fminf(127.0f, fmaxf(-127.0f, rintf(v * XSCALE)));
  return (int)qf;
}

// ---------------- prepass: x f32 -> i8 (fixed scale) ----------------
__global__ void quant_x_kernel(const float* __restrict__ x,
                               signed char* __restrict__ xq) {
  const size_t total = (size_t)M_DIM * K_DIM / 16;
  for (size_t u = (size_t)blockIdx.x * blockDim.x + threadIdx.x; u < total;
       u += (size_t)gridDim.x * blockDim.x) {
    const float4* src = (const float4*)(x + u * 16);
    int4 o;
    int* op = (int*)&o;
#pragma unroll
    for (int i = 0; i < 4; ++i) {
      float4 f = src[i];
      int q0 = q127(f.x), q1 = q127(f.y), q2 = q127(f.z), q3 = q127(f.w);
      op[i] = (q0 & 255) | ((q1 & 255) << 8) | ((q2 & 255) << 16) | ((q3 & 255) << 24);
    }
    *(int4*)(xq + u * 16) = o;
  }
}

// ---------------- prepass: packed int4 -> i8 W [N, K] (no scale: exact) ----------------
__global__ void unpack_w_kernel(const int* __restrict__ q,
                                signed char* __restrict__ W) {
  const size_t total = (size_t)N_DIM * KB2 / 8;  // 8 int32 -> 16 i8 per iter
  for (size_t u = (size_t)blockIdx.x * blockDim.x + threadIdx.x; u < total;
       u += (size_t)gridDim.x * blockDim.x) {
    size_t qi = u * 8;
    int4 v0 = *(const int4*)(q + qi);
    int4 v1 = *(const int4*)(q + qi + 4);
    int4 o;
    int* op = (int*)&o;
    const int* vp = (const int*)&v0;
#pragma unroll
    for (int i = 0; i < 2; ++i) {
      const int* vv = i ? (const int*)&v1 : vp;
#pragma unroll
      for (int p = 0; p < 2; ++p) {
        int a = vv[p * 2], b = vv[p * 2 + 1];
        int b0 = (a & 15) - 8, b1 = ((a >> 4) & 15) - 8;
        int b2 = (b & 15) - 8, b3 = ((b >> 4) & 15) - 8;
        op[i * 2 + p] = (b0 & 255) | ((b1 & 255) << 8) | ((b2 & 255) << 16) | ((b3 & 255) << 24);
      }
    }
    *(int4*)(W + qi * 2) = o;
  }
}

// ---------------- prepass: transpose scales -> sT[g][o] ----------------
__global__ void transpose_s_kernel(const float* __restrict__ s,
                                   float* __restrict__ sT) {
  const int total = NGRP * N_DIM;
  for (int u = blockIdx.x * blockDim.x + threadIdx.x; u < total;
       u += gridDim.x * blockDim.x) {
    int g = u / N_DIM, o = u - g * N_DIM;
    sT[u] = s[o * NGRP + g];  // write coalesced, read strided (1.4MB, cheap)
  }
}

// ---------------- main GEMM: C = Xq[M,K]i8 * Wq[N,K]^T i8 + group fixup + bias ----------------
// 128x256 tile, BK=64, 8 waves (2M x 4N), per-wave 64x64: iacc[4][4] (i32) + facc[4][4] (f32).
// mfma_i32_16x16x64_i8: one b128 LDS read per operand frag covers K=64.
// Group (128 K) = 2 K-steps: i32-accumulate, then facc += (float)iacc * s[o][g], iacc=0.
// Scales for the block's 256 cols staged to LDS once (32KB) -> fixup reads are ds_read_b32.
// R5-verified skeleton: 3 buffers, distance-2 prefetch, counted vmcnt(3) (3 loads/tile),
// both-sides swizzle for 64B rows (4 x 16B slots): f(row) = (row>>1)&3.
__global__ __launch_bounds__(512, 2) void gemm_i8_kernel(
    const signed char* __restrict__ A, const signed char* __restrict__ B,
    const float* __restrict__ sT, const float* __restrict__ bias,
    float* __restrict__ C) {
  __shared__ signed char lds[3 * BUF_B + 32768];  // 104 KB
  float* sLds = (float*)(lds + SLDS_OFF);

  const int tid = threadIdx.x;
  const int w = tid >> 6, lane = tid & 63;

  // T1: XCD-chunked bijective swizzle (688 = 8 * 86), m-fast within XCD.
  const int hw = blockIdx.x;
  const int wg = (hw & 7) * 86 + (hw >> 3);
  const int m0 = (wg % 16) * TBM;
  const int n0 = (wg / 16) * TBN;

  // scale tile: sLds[g*256 + c] = sT[g][n0 + c]  (8192 floats, 16 per thread)
#pragma unroll
  for (int i = 0; i < 16; ++i) {
    int idx = tid + i * 512;
    int g = idx >> 8, c = idx & 255;
    sLds[idx] = sT[g * N_DIM + n0 + c];
  }

  // staging: 3 issues/tile (A 8KB, B 2x8KB); thread covers row tid>>2, slot tid&3.
  // Inverse swizzle on global k: slot s of row r holds k-chunk s ^ ((r>>1)&3).
  const int srow = tid >> 2;
  const int kx = (((tid & 3) ^ ((tid >> 3) & 3)) << 4);  // bytes
  const signed char* Ag = A + (size_t)(m0 + srow) * K_DIM + kx;
  const signed char* Bg = B + (size_t)(n0 + srow) * K_DIM + kx;
  const int wBase = w * 1024;  // wave-uniform LDS staging base (bytes)

#define STAGE(bufo, t2) {                                                      \
    const signed char* a_ = Ag + (size_t)(t2) * TBK;                           \
    const signed char* b_ = Bg + (size_t)(t2) * TBK;                           \
    gload_lds16(a_,                       lds + (bufo) + wBase);               \
    gload_lds16(b_,                       lds + (bufo) + 8192 + wBase);        \
    gload_lds16(b_ + (size_t)128 * K_DIM, lds + (bufo) + 16384 + wBase);       \
  }

  // ds_read addressing (swizzled): byte addr = row*64 + (lq ^ ((row>>1)&3))*16
  const int lane16 = lane & 15, lq = lane >> 4;
  const int wm = (w >> 2) * 64, wn = (w & 3) * 64;
  const int kOfsB = ((lq ^ ((lane16 >> 1) & 3)) << 4);
  int aOff[4], bOff[4];
#pragma unroll
  for (int i = 0; i < 4; ++i) aOff[i] = (wm + i * 16 + lane16) * 64 + kOfsB;
#pragma unroll
  for (int j = 0; j < 4; ++j) bOff[j] = 8192 + (wn + j * 16 + lane16) * 64 + kOfsB;

  const i32x4 zero4 = {0, 0, 0, 0};
  i32x4 iacc[4][4];
  f32x4 facc[4][4] = {};
#pragma unroll
  for (int i = 0; i < 4; ++i)
#pragma unroll
    for (int j = 0; j < 4; ++j) iacc[i][j] = zero4;
  float sv[4];

  // prologue: stage tiles 0,1 (6 loads); wait tile 0 (+ scale loads drained)
  STAGE(0, 0);
  STAGE(BUF_B, 1);
  asm volatile("s_waitcnt vmcnt(3) lgkmcnt(0)" ::: "memory");
  __builtin_amdgcn_s_barrier();

  int cur = 0, stg = 2 * BUF_B;
  for (int t = 0; t < NT; ++t) {
    if (t + 2 < NT) STAGE(stg, t + 2);

    const signed char* Lb = lds + cur;
    i32x4 av[4], bv[4];
#pragma unroll
    for (int i = 0; i < 4; ++i) av[i] = *(const i32x4*)(Lb + aOff[i]);
#pragma unroll
    for (int j = 0; j < 4; ++j) bv[j] = *(const i32x4*)(Lb + bOff[j]);

    if (!(t & 1)) {  // group start: fetch this group's scales from LDS
      const int g = t >> 1;
#pragma unroll
      for (int nf = 0; nf < 4; ++nf)
        sv[nf] = sLds[g * 256 + wn + nf * 16 + lane16];
    }

    __builtin_amdgcn_s_setprio(1);
#pragma unroll
    for (int i = 0; i < 4; ++i)
#pragma unroll
      for (int j = 0; j < 4; ++j)
        iacc[i][j] = __builtin_amdgcn_mfma_i32_16x16x64_i8(av[i], bv[j], iacc[i][j], 0, 0, 0);
    __builtin_amdgcn_s_setprio(0);

    if (t & 1) {  // group end (128 K accumulated): exact f32 fixup
#pragma unroll
      for (int i = 0; i < 4; ++i)
#pragma unroll
        for (int j = 0; j < 4; ++j) {
#pragma unroll
          for (int r = 0; r < 4; ++r)
            facc[i][j][r] += (float)iacc[i][j][r] * sv[j];
          iacc[i][j] = zero4;
        }
    }

    if (t == NT - 1) break;
    if (t == NT - 2) {
      asm volatile("s_waitcnt vmcnt(0)" ::: "memory");  // final tile must land
    } else {
      asm volatile("s_waitcnt vmcnt(3)" ::: "memory");  // keep tile t+2 in flight
    }
    __builtin_amdgcn_s_barrier();
    cur = (cur == 2 * BUF_B) ? 0 : cur + BUF_B;
    stg = (stg == 2 * BUF_B) ? 0 : stg + BUF_B;
  }
#undef STAGE

  // epilogue: D mapping col=lane&15, row=(lane>>4)*4+r ; out = facc*Delta + bias
  const int row0 = m0 + wm + (lane >> 4) * 4;
  const int col0 = n0 + wn + lane16;
#pragma unroll
  for (int j = 0; j < 4; ++j) {
    float bvs = bias[col0 + j * 16];
#pragma unroll
    for (int i = 0; i < 4; ++i) {
#pragma unroll
      for (int r = 0; r < 4; ++r) {
        C[(size_t)(row0 + i * 16 + r) * N_DIM + (col0 + j * 16)] =
            facc[i][j][r] * XINV + bvs;
      }
    }
  }
}

// ---------------- fallback: fused bf16 dequant GEMM (no workspace needed) ----------------
__global__ __launch_bounds__(256, 2) void gemm_fused_kernel(
    const float* __restrict__ x, const int* __restrict__ q,
    const float* __restrict__ s, const float* __restrict__ bias,
    float* __restrict__ C) {
  __shared__ unsigned short As[BM * BK];
  __shared__ unsigned short Bs[BN * BK];

  const int tid = threadIdx.x;
  const int wave = tid >> 6, lane = tid & 63;
  const int m0 = blockIdx.y * BM, n0 = blockIdx.x * BN;
  const int wm = (wave >> 1) * 64, wn = (wave & 1) * 64;

  f32x4 acc[4][4] = {};

  const int r2 = tid >> 1;
  const int kh = (tid & 1) * 32;
  const float* xg = x + (size_t)(m0 + r2) * K_DIM + kh;
  const int* qg = q + (size_t)(n0 + r2) * KB2 + (tid & 1) * 16;
  const float* sg = s + (size_t)(n0 + r2) * NGRP;
  unsigned short* Asp = &As[r2 * BK + kh];
  unsigned short* Bsp = &Bs[r2 * BK + kh];

  const int lane16 = lane & 15;
  const int kq = (lane >> 4) * 8;

  for (int t = 0; t < K_DIM / BK; ++t) {
    union { unsigned short h[8]; bf16x8 v; } oA[4], oB[4];
#pragma unroll
    for (int j = 0; j < 4; ++j) {
      float4 f0 = *(const float4*)(xg + t * BK + j * 8);
      float4 f1 = *(const float4*)(xg + t * BK + j * 8 + 4);
      oA[j].h[0] = f2bf(f0.x); oA[j].h[1] = f2bf(f0.y); oA[j].h[2] = f2bf(f0.z); oA[j].h[3] = f2bf(f0.w);
      oA[j].h[4] = f2bf(f1.x); oA[j].h[5] = f2bf(f1.y); oA[j].h[6] = f2bf(f1.z); oA[j].h[7] = f2bf(f1.w);
    }
    float sc = sg[t >> 1];
#pragma unroll
    for (int j = 0; j < 4; ++j) {
      int4 qv = *(const int4*)(qg + t * 32 + j * 4);
      int b;
      b = qv.x; oB[j].h[0] = f2bf((float)((b & 15) - 8) * sc); oB[j].h[1] = f2bf((float)(((b >> 4) & 15) - 8) * sc);
      b = qv.y; oB[j].h[2] = f2bf((float)((b & 15) - 8) * sc); oB[j].h[3] = f2bf((float)(((b >> 4) & 15) - 8) * sc);
      b = qv.z; oB[j].h[4] = f2bf((float)((b & 15) - 8) * sc); oB[j].h[5] = f2bf((float)(((b >> 4) & 15) - 8) * sc);
      b = qv.w; oB[j].h[6] = f2bf((float)((b & 15) - 8) * sc); oB[j].h[7] = f2bf((float)(((b >> 4) & 15) - 8) * sc);
    }
    __syncthreads();
#pragma unroll
    for (int j = 0; j < 4; ++j) {
      *(bf16x8*)(Asp + j * 8) = oA[j].v;
      *(bf16x8*)(Bsp + j * 8) = oB[j].v;
    }
    __syncthreads();
#pragma unroll
    for (int kk = 0; kk < 2; ++kk) {
      const int ko = kk * 32 + kq;
      bf16x8 av[4], bv[4];
#pragma unroll
      for (int i = 0; i < 4; ++i)
        av[i] = *(const bf16x8*)&As[(wm + i * 16 + lane16) * BK + ko];
#pragma unroll
      for (int i = 0; i < 4; ++i)
        bv[i] = *(const bf16x8*)&Bs[(wn + i * 16 + lane16) * BK + ko];
#pragma unroll
      for (int i = 0; i < 4; ++i)
#pragma unroll
        for (int j = 0; j < 4; ++j)
          acc[i][j] = __builtin_amdgcn_mfma_f32_16x16x32_bf16(av[i], bv[j], acc[i][j], 0, 0, 0);
    }
  }

  const int col0 = n0 + wn + lane16;
  const int row0 = m0 + wm + (lane >> 4) * 4;
#pragma unroll
  for (int j = 0; j < 4; ++j) {
    float bvs = bias[col0 + j * 16];
#pragma unroll
    for (int i = 0; i < 4; ++i) {
#pragma unroll
      for (int r = 0; r < 4; ++r) {
        C[(size_t)(row0 + i * 16 + r) * N_DIM + (col0 + j * 16)] = acc[i][j][r] + bvs;
      }
    }
  }
}

extern "C" void kernel_launch(void* const* d_in, const int* in_sizes, int n_in,
                              void* d_out, int out_size, void* d_ws, size_t ws_size,
                              hipStream_t stream) {
  const float* x = (const float*)d_in[0];
  const int* q = (const int*)d_in[1];
  const float* s = (const float*)d_in[2];
  const float* b = (const float*)d_in[3];
  float* out = (float*)d_out;

  const size_t w_bytes = (size_t)N_DIM * K_DIM;          // 45,088,768 (i8 W)
  const size_t x_bytes = (size_t)M_DIM * K_DIM;          // 8,388,608  (i8 x)
  const size_t s_bytes = (size_t)NGRP * N_DIM * 4;       // 1,409,024  (sT f32)
  const size_t need = w_bytes + x_bytes + s_bytes;       // ~55 MB

  if (ws_size >= need) {
    signed char* Wq = (signed char*)d_ws;
    signed char* Xq = Wq + w_bytes;
    float* sT = (float*)(Wq + w_bytes + x_bytes);
    quant_x_kernel<<<dim3(2048), dim3(256), 0, stream>>>(x, Xq);
    unpack_w_kernel<<<dim3(2048), dim3(256), 0, stream>>>(q, Wq);
    transpose_s_kernel<<<dim3(1376), dim3(256), 0, stream>>>(s, sT);
    gemm_i8_kernel<<<dim3((N_DIM / TBN) * (M_DIM / TBM)), dim3(512), 0, stream>>>(Xq, Wq, sT, b, out);
  } else {
    gemm_fused_kernel<<<dim3(N_DIM / BN, M_DIM / BM), dim3(256), 0, stream>>>(x, q, s, b, out);
  }
}